// Round 14
// baseline (566.155 us; speedup 1.0000x reference)
//
#include <hip/hip_runtime.h>
#include <cstdint>

#define NN 16384
#define FF 128
#define RR 16
#define HH 8
#define CC 64
#define HC 512
#define NC 1024          // fused Wl|Wr output width
#define EE 163840
#define ET (EE + NN)     // 180224 edges including self-loops (64-divisible)

typedef __attribute__((ext_vector_type(2))) float f32x2;
typedef __attribute__((ext_vector_type(4))) float f32x4;
typedef __attribute__((ext_vector_type(8))) short short8;

__device__ __forceinline__ unsigned short f2bf(float f) {
  unsigned u = __builtin_bit_cast(unsigned, f);
  u = (u + 0x7FFFu + ((u >> 16) & 1u)) >> 16;   // RNE
  return (unsigned short)u;
}
__device__ __forceinline__ float bf2f(unsigned short b) {
  unsigned u = ((unsigned)b) << 16;
  return __builtin_bit_cast(float, u);
}
__device__ __forceinline__ unsigned short f2h(float f) {
  return __builtin_bit_cast(unsigned short, (_Float16)f);
}
__device__ __forceinline__ float h2f(unsigned short h) {
  return (float)__builtin_bit_cast(_Float16, h);
}

__device__ __forceinline__ void gl_lds16(const void* g, void* l) {
  __builtin_amdgcn_global_load_lds(
      (const __attribute__((address_space(1))) unsigned int*)g,
      (__attribute__((address_space(3))) unsigned int*)l, 16, 0, 0);
}

// ---------------- CSR build (dst-sorted) ----------------
__global__ __launch_bounds__(256) void count_kernel(const int* __restrict__ ei,
                                                    int* __restrict__ counts) {
  int e = blockIdx.x * 256 + threadIdx.x;
  if (e >= ET) return;
  int d = (e < EE) ? ei[EE + e] : (e - EE);
  atomicAdd(&counts[d], 1);
}

__global__ __launch_bounds__(1024) void scan_kernel(const int* __restrict__ counts,
                                                    int* __restrict__ offs,
                                                    int* __restrict__ cursor) {
  __shared__ int part[1024];
  int t = threadIdx.x;
  int base = t * 16;
  int loc[16];
  int s = 0;
#pragma unroll
  for (int i = 0; i < 16; ++i) { loc[i] = s; s += counts[base + i]; }
  part[t] = s;
  __syncthreads();
  for (int off = 1; off < 1024; off <<= 1) {
    int v = (t >= off) ? part[t - off] : 0;
    __syncthreads();
    part[t] += v;
    __syncthreads();
  }
  int excl = part[t] - s;
#pragma unroll
  for (int i = 0; i < 16; ++i) {
    int o = excl + loc[i];
    offs[base + i] = o;
    cursor[base + i] = o;
  }
  if (t == 1023) offs[NN] = part[1023];
}

// pack (edge, src) into one int2 per CSR slot
__global__ __launch_bounds__(256) void scatter_kernel(const int* __restrict__ ei,
                                                      int* __restrict__ cursor,
                                                      int2* __restrict__ esrc) {
  int e = blockIdx.x * 256 + threadIdx.x;
  if (e >= ET) return;
  int s, d;
  if (e < EE) { s = ei[e]; d = ei[EE + e]; }
  else        { s = d = e - EE; }
  int p = atomicAdd(&cursor[d], 1);
  esrc[p] = make_int2(e, s);
}

// ---------------- packing: fp32 -> split bf16 (hi/lo), k-chunk-tiled + swizzled ----------------
__global__ __launch_bounds__(256) void pack_a_kernel(const float* __restrict__ A,
                                                     unsigned short* __restrict__ Ah,
                                                     unsigned short* __restrict__ Al,
                                                     int K) {
  int nkb = K >> 5;
  int rb = blockIdx.x / nkb, kb = blockIdx.x % nkb;
  int t = threadIdx.x;
  size_t obase = ((size_t)rb * nkb + kb) * 4096;
#pragma unroll
  for (int u = 0; u < 2; ++u) {
    int lin = t + u * 256;          // r*4 + ch
    int r = lin >> 2, ch = lin & 3;
    int chs = (ch + (r >> 1)) & 3;
    const float* src = &A[(size_t)(rb * 128 + r) * K + kb * 32 + ch * 8];
    float4 v0 = *(const float4*)src;
    float4 v1 = *(const float4*)(src + 4);
    float v[8] = {v0.x, v0.y, v0.z, v0.w, v1.x, v1.y, v1.z, v1.w};
    short8 hv, lv;
#pragma unroll
    for (int j = 0; j < 8; ++j) {
      unsigned short h = f2bf(v[j]);
      unsigned short l = f2bf(v[j] - bf2f(h));
      hv[j] = (short)h; lv[j] = (short)l;
    }
    size_t o = obase + (size_t)r * 32 + chs * 8;
    *(short8*)&Ah[o] = hv;
    *(short8*)&Al[o] = lv;
  }
}

__global__ __launch_bounds__(256) void pack_w_kernel(const float* __restrict__ Wl,
                                                     const float* __restrict__ Wr,
                                                     unsigned short* __restrict__ Bh,
                                                     unsigned short* __restrict__ Bl,
                                                     int K) {
  int nkb = K >> 5;
  int nb = blockIdx.x / nkb, kb = blockIdx.x % nkb;
  int t = threadIdx.x;
  size_t obase = ((size_t)nb * nkb + kb) * 4096;
#pragma unroll
  for (int u = 0; u < 2; ++u) {
    int lin = t + u * 256;          // n*4 + ch
    int n = lin >> 2, ch = lin & 3;
    int chs = (ch + (n >> 1)) & 3;
    int gn = nb * 128 + n;
    const float* W = (gn < HC) ? Wl : Wr;
    int cn = gn & (HC - 1);
    short8 hv, lv;
#pragma unroll
    for (int j = 0; j < 8; ++j) {
      float f = W[(size_t)(kb * 32 + ch * 8 + j) * HC + cn];
      unsigned short h = f2bf(f);
      unsigned short l = f2bf(f - bf2f(h));
      hv[j] = (short)h; lv[j] = (short)l;
    }
    size_t o = obase + (size_t)n * 32 + chs * 8;
    *(short8*)&Bh[o] = hv;
    *(short8*)&Bl[o] = lv;
  }
}

// ---------------- transpose We -> WeT[512 cols][16 rows] fp32 ----------------
__global__ __launch_bounds__(256) void pack_wet_kernel(const float* __restrict__ We,
                                                       float* __restrict__ WeT) {
  int i = blockIdx.x * 256 + threadIdx.x;   // 8192 = 512*16; i = c*16 + r
  int c = i >> 4, r = i & 15;
  WeT[i] = We[r * HC + c];
}

// ---------------- split-bf16 MFMA GEMM: C[M x 1024] = A[M x K] @ [Wl|Wr] + [bl|br] ----------------
// xl half (col<HC) stored ONLY as fp16 to Chh (fused reads xlh; rv reads col>=HC).
__global__ __launch_bounds__(256) void gemm_mfma_kernel(const unsigned short* __restrict__ Ah,
                                                        const unsigned short* __restrict__ Al,
                                                        const unsigned short* __restrict__ Bh,
                                                        const unsigned short* __restrict__ Bl,
                                                        const float* __restrict__ bl,
                                                        const float* __restrict__ br,
                                                        float* __restrict__ C,
                                                        unsigned short* __restrict__ Chh,
                                                        int K) {
  __shared__ unsigned short lAh[4096], lAl[4096], lBh[4096], lBl[4096];
  int tid = threadIdx.x;
  int wave = tid >> 6, lane = tid & 63;
  int l15 = lane & 15, quad = lane >> 4;
  int wm = wave >> 1, wn = wave & 1;
  int nb = blockIdx.x, rb = blockIdx.y;
  int nkb = K >> 5;

  const unsigned short* src = (wave == 0) ? Ah : (wave == 1) ? Al : (wave == 2) ? Bh : Bl;
  unsigned short* dst = (wave == 0) ? lAh : (wave == 1) ? lAl : (wave == 2) ? lBh : lBl;
  int blk = (wave < 2) ? rb : nb;
  size_t gstep = 4096;
  const unsigned short* gbase = src + ((size_t)blk * nkb) * gstep + lane * 8;

  f32x4 acc[4][4];
#pragma unroll
  for (int i = 0; i < 4; ++i)
#pragma unroll
    for (int j = 0; j < 4; ++j) acc[i][j] = (f32x4){0.f, 0.f, 0.f, 0.f};

  int offA[4], offB[4];
#pragma unroll
  for (int t = 0; t < 4; ++t) {
    int ra = wm * 64 + t * 16 + l15;
    offA[t] = ra * 32 + ((quad + (ra >> 1)) & 3) * 8;
    int rbn = wn * 64 + t * 16 + l15;
    offB[t] = rbn * 32 + ((quad + (rbn >> 1)) & 3) * 8;
  }

  for (int kb = 0; kb < nkb; ++kb) {
    const unsigned short* g = gbase + (size_t)kb * gstep;
#pragma unroll
    for (int i = 0; i < 8; ++i)
      gl_lds16(g + i * 512, dst + i * 512);
    __syncthreads();

    short8 ah[4], al_[4], bh[4], bl_[4];
#pragma unroll
    for (int t = 0; t < 4; ++t) {
      ah[t]  = *(const short8*)&lAh[offA[t]];
      al_[t] = *(const short8*)&lAl[offA[t]];
      bh[t]  = *(const short8*)&lBh[offB[t]];
      bl_[t] = *(const short8*)&lBl[offB[t]];
    }
#pragma unroll
    for (int tm = 0; tm < 4; ++tm)
#pragma unroll
      for (int tn = 0; tn < 4; ++tn) {
        acc[tm][tn] = __builtin_amdgcn_mfma_f32_16x16x32_bf16(ah[tm], bh[tn], acc[tm][tn], 0, 0, 0);
        acc[tm][tn] = __builtin_amdgcn_mfma_f32_16x16x32_bf16(ah[tm], bl_[tn], acc[tm][tn], 0, 0, 0);
        acc[tm][tn] = __builtin_amdgcn_mfma_f32_16x16x32_bf16(al_[tm], bh[tn], acc[tm][tn], 0, 0, 0);
      }
    __syncthreads();
  }

#pragma unroll
  for (int tm = 0; tm < 4; ++tm) {
    int row = rb * 128 + wm * 64 + tm * 16 + quad * 4;
#pragma unroll
    for (int tn = 0; tn < 4; ++tn) {
      int col = nb * 128 + wn * 64 + tn * 16 + l15;
      bool xlh_half = (col < HC);            // uniform per block (nb<4)
      float bias = xlh_half ? bl[col] : br[col - HC];
#pragma unroll
      for (int r = 0; r < 4; ++r) {
        float v = acc[tm][tn][r] + bias;
        if (xlh_half)
          Chh[(size_t)(row + r) * HC + col] = f2h(v);
        else
          C[(size_t)(row + r) * NC + col] = v;
      }
    }
  }
}

// ================= R14: fused kernel — 2 nodes/block, 4 channels/thread =================
// R13 verdict: issue-bound at 256 thr/node; per edge ALL 256 threads redundantly
// issue the same esrc + eattr broadcast loads and per-thread online-update VALU.
// R14 halves the redundancy: 128 threads/node (4 ch/thread), 2 nodes per 256-block
// (each node = 2 whole waves -> loop counts wave-uniform). Per-edge issue volume:
// VMEM 5632->2688, shfl 5/thread->4/thread on half the threads, update VALU halved.
// Total FMA work unchanged. Math identical (same online softmax).

__device__ __forceinline__ f32x4 lrelu4(f32x4 z) {
  f32x4 zn = __builtin_elementwise_min(z, (f32x4){0.f, 0.f, 0.f, 0.f});
  f32x4 zp = __builtin_elementwise_max(z, (f32x4){0.f, 0.f, 0.f, 0.f});
  return __builtin_elementwise_fma((f32x4){0.2f, 0.2f, 0.2f, 0.2f}, zn, zp);
}

__device__ __forceinline__ void fused_edge_body4(
    const int2* __restrict__ esrc,
    const int* __restrict__ offs, const float* __restrict__ eattr,
    const float* __restrict__ WeT, const float* __restrict__ att,
    const float* __restrict__ xlr, const unsigned short* __restrict__ xlh,
    int n, int tt /*0..127*/, f32x4& outv) {
  int c0 = tt * 4;
  int beg = offs[n], end = offs[n + 1];
  // wf: 16 f32x4 = 64 consecutive floats = columns c0..c0+3 of WeT
  f32x4 w[16];
  {
    const f32x4* wp = (const f32x4*)&WeT[(size_t)c0 * RR];
#pragma unroll
    for (int k = 0; k < 16; ++k) w[k] = wp[k];
  }
  f32x4 amv = *(const f32x4*)&att[c0];
  f32x4 rv  = *(const f32x4*)&xlr[(size_t)n * NC + HC + c0];  // dst row: once
  float m = -1e30f, l = 0.f;
  f32x4 acc = (f32x4){0.f, 0.f, 0.f, 0.f};
#pragma unroll 2
  for (int i = beg; i < end; ++i) {
    int2 es = esrc[i];              // 8B broadcast (uniform addr across wave)
    int e = es.x, s = es.y;
    // 4 fp16 channels = one 8B load
    ushort4 lu = *(const ushort4*)&xlh[(size_t)s * HC + c0];
    f32x4 lv = (f32x4){h2f(lu.x), h2f(lu.y), h2f(lu.z), h2f(lu.w)};
    f32x4 ea0, ea1, ea2, ea3;
    if (e < EE) {
      const f32x4* ep4 = (const f32x4*)&eattr[(size_t)e * RR];
      ea0 = ep4[0]; ea1 = ep4[1]; ea2 = ep4[2]; ea3 = ep4[3];
    } else {
      ea0 = ea1 = ea2 = ea3 = (f32x4){0.5f, 0.5f, 0.5f, 0.5f};
    }
    f32x4 q0 = (f32x4){0.f, 0.f, 0.f, 0.f};
    f32x4 q1 = q0, q2 = q0, q3 = q0;
    q0 = __builtin_elementwise_fma(ea0, w[0],  q0);
    q0 = __builtin_elementwise_fma(ea1, w[1],  q0);
    q0 = __builtin_elementwise_fma(ea2, w[2],  q0);
    q0 = __builtin_elementwise_fma(ea3, w[3],  q0);
    q1 = __builtin_elementwise_fma(ea0, w[4],  q1);
    q1 = __builtin_elementwise_fma(ea1, w[5],  q1);
    q1 = __builtin_elementwise_fma(ea2, w[6],  q1);
    q1 = __builtin_elementwise_fma(ea3, w[7],  q1);
    q2 = __builtin_elementwise_fma(ea0, w[8],  q2);
    q2 = __builtin_elementwise_fma(ea1, w[9],  q2);
    q2 = __builtin_elementwise_fma(ea2, w[10], q2);
    q2 = __builtin_elementwise_fma(ea3, w[11], q2);
    q3 = __builtin_elementwise_fma(ea0, w[12], q3);
    q3 = __builtin_elementwise_fma(ea1, w[13], q3);
    q3 = __builtin_elementwise_fma(ea2, w[14], q3);
    q3 = __builtin_elementwise_fma(ea3, w[15], q3);
    f32x4 ep = (f32x4){(q0.x + q0.y) + (q0.z + q0.w),
                       (q1.x + q1.y) + (q1.z + q1.w),
                       (q2.x + q2.y) + (q2.z + q2.w),
                       (q3.x + q3.y) + (q3.z + q3.w)};
    f32x4 z = lrelu4(lv + rv + ep);
    float p = fmaf(z.x, amv.x, fmaf(z.y, amv.y, fmaf(z.z, amv.z, z.w * amv.w)));
    // head = c0>>6 = tt>>4 -> 16-lane groups, within-wave
    p += __shfl_xor(p, 1);
    p += __shfl_xor(p, 2);
    p += __shfl_xor(p, 4);
    p += __shfl_xor(p, 8);
    float nm = fmaxf(m, p);
    float sc = __expf(m - nm);
    float el = __expf(p - nm);
    l = l * sc + el;
    f32x4 scv = (f32x4){sc, sc, sc, sc};
    f32x4 elv = (f32x4){el, el, el, el};
    acc = __builtin_elementwise_fma(acc, scv, elv * lv);
    m = nm;
  }
  float inv = 1.f / (l + 1e-16f);
  outv = acc * (f32x4){inv, inv, inv, inv};
}

// layer 1: +bias, emit packed split-bf16 A for layer-2 GEMM. 2 nodes/block.
__global__ __launch_bounds__(256) void fused_concat_kernel(
    const int2* __restrict__ esrc,
    const int* __restrict__ offs, const float* __restrict__ eattr,
    const float* __restrict__ WeT, const float* __restrict__ att,
    const float* __restrict__ xlr, const unsigned short* __restrict__ xlh,
    const float* __restrict__ bias,
    unsigned short* __restrict__ Ah2, unsigned short* __restrict__ Al2) {
  int t = threadIdx.x;
  int half = t >> 7, tt = t & 127;
  int n = blockIdx.x * 2 + half;
  f32x4 o;
  fused_edge_body4(esrc, offs, eattr, WeT, att, xlr, xlh, n, tt, o);
  int c0 = tt * 4;
  int r = n & 127, rbk = n >> 7;
  float ov[4] = {o.x, o.y, o.z, o.w};
#pragma unroll
  for (int u = 0; u < 4; ++u) {
    int c = c0 + u;
    float v = ov[u] + bias[c];
    int kb = c >> 5, ch = (c >> 3) & 3, j = c & 7;
    int chs = (ch + (r >> 1)) & 3;
    size_t idx = ((size_t)rbk * 16 + kb) * 4096 + (size_t)r * 32 + chs * 8 + j;
    unsigned short h = f2bf(v);
    Ah2[idx] = h;
    Al2[idx] = f2bf(v - bf2f(h));
  }
}

// layer 2: mean over heads + bias2 -> out. 2 nodes/block.
__global__ __launch_bounds__(256) void fused_mean_kernel(
    const int2* __restrict__ esrc,
    const int* __restrict__ offs, const float* __restrict__ eattr,
    const float* __restrict__ WeT, const float* __restrict__ att,
    const float* __restrict__ xlr, const unsigned short* __restrict__ xlh,
    const float* __restrict__ bias2, float* __restrict__ out) {
  __shared__ float red[2][HC];
  int t = threadIdx.x;
  int half = t >> 7, tt = t & 127;
  int n = blockIdx.x * 2 + half;
  f32x4 o;
  fused_edge_body4(esrc, offs, eattr, WeT, att, xlr, xlh, n, tt, o);
  int c0 = tt * 4;
  *(f32x4*)&red[half][c0] = o;
  __syncthreads();
  if (tt < CC) {
    float ssum = 0.f;
#pragma unroll
    for (int hh = 0; hh < HH; ++hh) ssum += red[half][hh * CC + tt];
    out[(size_t)n * CC + tt] = ssum * 0.125f + bias2[tt];
  }
}

extern "C" void kernel_launch(void* const* d_in, const int* in_sizes, int n_in,
                              void* d_out, int out_size, void* d_ws, size_t ws_size,
                              hipStream_t stream) {
  const float* x     = (const float*)d_in[0];
  const int*   ei    = (const int*)d_in[1];
  const float* eattr = (const float*)d_in[2];
  const float* Wl1   = (const float*)d_in[3];
  const float* bl1   = (const float*)d_in[4];
  const float* Wr1   = (const float*)d_in[5];
  const float* br1   = (const float*)d_in[6];
  const float* We1   = (const float*)d_in[7];
  const float* att1  = (const float*)d_in[8];
  const float* bias1 = (const float*)d_in[9];
  const float* Wl2   = (const float*)d_in[10];
  const float* bl2   = (const float*)d_in[11];
  const float* Wr2   = (const float*)d_in[12];
  const float* br2   = (const float*)d_in[13];
  const float* We2   = (const float*)d_in[14];
  const float* att2  = (const float*)d_in[15];
  const float* bias2 = (const float*)d_in[16];
  float* out = (float*)d_out;

  char* ws = (char*)d_ws;
  size_t off = 0;
  auto alloc = [&](size_t bytes) {
    char* p = ws + off;
    off += (bytes + 255) & ~(size_t)255;
    return p;
  };
  float* bufC = (float*)alloc((size_t)NN * NC * 4);            // fused xl|xr (both layers)
  unsigned short* xlh = (unsigned short*)alloc((size_t)NN * HC * 2);  // fp16 xl copy (gather path)
  unsigned short* Ah1 = (unsigned short*)alloc((size_t)NN * FF * 2);
  unsigned short* Al1 = (unsigned short*)alloc((size_t)NN * FF * 2);
  unsigned short* Ah2 = (unsigned short*)alloc((size_t)NN * HC * 2);
  unsigned short* Al2 = (unsigned short*)alloc((size_t)NN * HC * 2);
  unsigned short* Wh1 = (unsigned short*)alloc((size_t)FF * NC * 2);
  unsigned short* Wlo1 = (unsigned short*)alloc((size_t)FF * NC * 2);
  unsigned short* Wh2 = (unsigned short*)alloc((size_t)HC * NC * 2);
  unsigned short* Wlo2 = (unsigned short*)alloc((size_t)HC * NC * 2);
  float* WeT1 = (float*)alloc((size_t)HC * RR * 4);            // We1^T fp32 [512][16]
  float* WeT2 = (float*)alloc((size_t)HC * RR * 4);            // We2^T fp32 [512][16]
  int* counts = (int*)alloc((size_t)NN * 4);
  int* offs   = (int*)alloc((size_t)(NN + 1) * 4);
  int* cursor = (int*)alloc((size_t)NN * 4);
  int2* esrc  = (int2*)alloc((size_t)ET * 8);                  // packed (edge, src) per CSR slot
  (void)ws_size; (void)in_sizes; (void)n_in; (void)out_size;

  // CSR build (every launch; ws is re-poisoned)
  hipMemsetAsync(counts, 0, (size_t)NN * 4, stream);
  int eb = (ET + 255) / 256;
  count_kernel<<<eb, 256, 0, stream>>>(ei, counts);
  scan_kernel<<<1, 1024, 0, stream>>>(counts, offs, cursor);
  scatter_kernel<<<eb, 256, 0, stream>>>(ei, cursor, esrc);

  // pack operands
  pack_a_kernel<<<(NN / 128) * (FF / 32), 256, 0, stream>>>(x, Ah1, Al1, FF);
  pack_w_kernel<<<(NC / 128) * (FF / 32), 256, 0, stream>>>(Wl1, Wr1, Wh1, Wlo1, FF);
  pack_w_kernel<<<(NC / 128) * (HC / 32), 256, 0, stream>>>(Wl2, Wr2, Wh2, Wlo2, HC);
  pack_wet_kernel<<<(HC * RR) / 256, 256, 0, stream>>>(We1, WeT1);
  pack_wet_kernel<<<(HC * RR) / 256, 256, 0, stream>>>(We2, WeT2);

  dim3 ggrid(NC / 128, NN / 128);

  // ---- layer 1 ----
  gemm_mfma_kernel<<<ggrid, 256, 0, stream>>>(Ah1, Al1, Wh1, Wlo1, bl1, br1, bufC, xlh, FF);
  fused_concat_kernel<<<NN / 2, 256, 0, stream>>>(esrc, offs, eattr, WeT1, att1, bufC, xlh, bias1, Ah2, Al2);

  // ---- layer 2 ----
  gemm_mfma_kernel<<<ggrid, 256, 0, stream>>>(Ah2, Al2, Wh2, Wlo2, bl2, br2, bufC, xlh, HC);
  fused_mean_kernel<<<NN / 2, 256, 0, stream>>>(esrc, offs, eattr, WeT2, att2, bufC, xlh, bias2, out);
}

// Round 15
// 441.915 us; speedup vs baseline: 1.2811x; 1.2811x over previous
//
#include <hip/hip_runtime.h>
#include <cstdint>

#define NN 16384
#define FF 128
#define RR 16
#define HH 8
#define CC 64
#define HC 512
#define NC 1024          // fused Wl|Wr output width
#define EE 163840
#define ET (EE + NN)     // 180224 edges including self-loops (64-divisible)

typedef __attribute__((ext_vector_type(2))) float f32x2;
typedef __attribute__((ext_vector_type(4))) float f32x4;
typedef __attribute__((ext_vector_type(8))) short short8;

__device__ __forceinline__ unsigned short f2bf(float f) {
  unsigned u = __builtin_bit_cast(unsigned, f);
  u = (u + 0x7FFFu + ((u >> 16) & 1u)) >> 16;   // RNE
  return (unsigned short)u;
}
__device__ __forceinline__ float bf2f(unsigned short b) {
  unsigned u = ((unsigned)b) << 16;
  return __builtin_bit_cast(float, u);
}
__device__ __forceinline__ unsigned short f2h(float f) {
  return __builtin_bit_cast(unsigned short, (_Float16)f);
}
__device__ __forceinline__ float h2f(unsigned short h) {
  return (float)__builtin_bit_cast(_Float16, h);
}

__device__ __forceinline__ void gl_lds16(const void* g, void* l) {
  __builtin_amdgcn_global_load_lds(
      (const __attribute__((address_space(1))) unsigned int*)g,
      (__attribute__((address_space(3))) unsigned int*)l, 16, 0, 0);
}

// ---------------- CSR build (dst-sorted) ----------------
__global__ __launch_bounds__(256) void count_kernel(const int* __restrict__ ei,
                                                    int* __restrict__ counts) {
  int e = blockIdx.x * 256 + threadIdx.x;
  if (e >= ET) return;
  int d = (e < EE) ? ei[EE + e] : (e - EE);
  atomicAdd(&counts[d], 1);
}

__global__ __launch_bounds__(1024) void scan_kernel(const int* __restrict__ counts,
                                                    int* __restrict__ offs,
                                                    int* __restrict__ cursor) {
  __shared__ int part[1024];
  int t = threadIdx.x;
  int base = t * 16;
  int loc[16];
  int s = 0;
#pragma unroll
  for (int i = 0; i < 16; ++i) { loc[i] = s; s += counts[base + i]; }
  part[t] = s;
  __syncthreads();
  for (int off = 1; off < 1024; off <<= 1) {
    int v = (t >= off) ? part[t - off] : 0;
    __syncthreads();
    part[t] += v;
    __syncthreads();
  }
  int excl = part[t] - s;
#pragma unroll
  for (int i = 0; i < 16; ++i) {
    int o = excl + loc[i];
    offs[base + i] = o;
    cursor[base + i] = o;
  }
  if (t == 1023) offs[NN] = part[1023];
}

__global__ __launch_bounds__(256) void scatter_kernel(const int* __restrict__ ei,
                                                      int* __restrict__ cursor,
                                                      int* __restrict__ csr,
                                                      int* __restrict__ srcc) {
  int e = blockIdx.x * 256 + threadIdx.x;
  if (e >= ET) return;
  int s, d;
  if (e < EE) { s = ei[e]; d = ei[EE + e]; }
  else        { s = d = e - EE; }
  int p = atomicAdd(&cursor[d], 1);
  csr[p] = e;
  srcc[p] = s;
}

// ---------------- packing: fp32 -> split bf16 (hi/lo), k-chunk-tiled + swizzled ----------------
__global__ __launch_bounds__(256) void pack_a_kernel(const float* __restrict__ A,
                                                     unsigned short* __restrict__ Ah,
                                                     unsigned short* __restrict__ Al,
                                                     int K) {
  int nkb = K >> 5;
  int rb = blockIdx.x / nkb, kb = blockIdx.x % nkb;
  int t = threadIdx.x;
  size_t obase = ((size_t)rb * nkb + kb) * 4096;
#pragma unroll
  for (int u = 0; u < 2; ++u) {
    int lin = t + u * 256;          // r*4 + ch
    int r = lin >> 2, ch = lin & 3;
    int chs = (ch + (r >> 1)) & 3;
    const float* src = &A[(size_t)(rb * 128 + r) * K + kb * 32 + ch * 8];
    float4 v0 = *(const float4*)src;
    float4 v1 = *(const float4*)(src + 4);
    float v[8] = {v0.x, v0.y, v0.z, v0.w, v1.x, v1.y, v1.z, v1.w};
    short8 hv, lv;
#pragma unroll
    for (int j = 0; j < 8; ++j) {
      unsigned short h = f2bf(v[j]);
      unsigned short l = f2bf(v[j] - bf2f(h));
      hv[j] = (short)h; lv[j] = (short)l;
    }
    size_t o = obase + (size_t)r * 32 + chs * 8;
    *(short8*)&Ah[o] = hv;
    *(short8*)&Al[o] = lv;
  }
}

__global__ __launch_bounds__(256) void pack_w_kernel(const float* __restrict__ Wl,
                                                     const float* __restrict__ Wr,
                                                     unsigned short* __restrict__ Bh,
                                                     unsigned short* __restrict__ Bl,
                                                     int K) {
  int nkb = K >> 5;
  int nb = blockIdx.x / nkb, kb = blockIdx.x % nkb;
  int t = threadIdx.x;
  size_t obase = ((size_t)nb * nkb + kb) * 4096;
#pragma unroll
  for (int u = 0; u < 2; ++u) {
    int lin = t + u * 256;          // n*4 + ch
    int n = lin >> 2, ch = lin & 3;
    int chs = (ch + (n >> 1)) & 3;
    int gn = nb * 128 + n;
    const float* W = (gn < HC) ? Wl : Wr;
    int cn = gn & (HC - 1);
    short8 hv, lv;
#pragma unroll
    for (int j = 0; j < 8; ++j) {
      float f = W[(size_t)(kb * 32 + ch * 8 + j) * HC + cn];
      unsigned short h = f2bf(f);
      unsigned short l = f2bf(f - bf2f(h));
      hv[j] = (short)h; lv[j] = (short)l;
    }
    size_t o = obase + (size_t)n * 32 + chs * 8;
    *(short8*)&Bh[o] = hv;
    *(short8*)&Bl[o] = lv;
  }
}

// ---------------- transpose We -> WeT[512 cols][16 rows] fp32 ----------------
__global__ __launch_bounds__(256) void pack_wet_kernel(const float* __restrict__ We,
                                                       float* __restrict__ WeT) {
  int i = blockIdx.x * 256 + threadIdx.x;   // 8192 = 512*16; i = c*16 + r
  int c = i >> 4, r = i & 15;
  WeT[i] = We[r * HC + c];
}

// ---------------- split-bf16 MFMA GEMM: C[M x 1024] = A[M x K] @ [Wl|Wr] + [bl|br] ----------------
// xl half (col<HC) stored ONLY as fp16 to Chh (fused reads xlh; rv reads col>=HC).
__global__ __launch_bounds__(256) void gemm_mfma_kernel(const unsigned short* __restrict__ Ah,
                                                        const unsigned short* __restrict__ Al,
                                                        const unsigned short* __restrict__ Bh,
                                                        const unsigned short* __restrict__ Bl,
                                                        const float* __restrict__ bl,
                                                        const float* __restrict__ br,
                                                        float* __restrict__ C,
                                                        unsigned short* __restrict__ Chh,
                                                        int K) {
  __shared__ unsigned short lAh[4096], lAl[4096], lBh[4096], lBl[4096];
  int tid = threadIdx.x;
  int wave = tid >> 6, lane = tid & 63;
  int l15 = lane & 15, quad = lane >> 4;
  int wm = wave >> 1, wn = wave & 1;
  int nb = blockIdx.x, rb = blockIdx.y;
  int nkb = K >> 5;

  const unsigned short* src = (wave == 0) ? Ah : (wave == 1) ? Al : (wave == 2) ? Bh : Bl;
  unsigned short* dst = (wave == 0) ? lAh : (wave == 1) ? lAl : (wave == 2) ? lBh : lBl;
  int blk = (wave < 2) ? rb : nb;
  size_t gstep = 4096;
  const unsigned short* gbase = src + ((size_t)blk * nkb) * gstep + lane * 8;

  f32x4 acc[4][4];
#pragma unroll
  for (int i = 0; i < 4; ++i)
#pragma unroll
    for (int j = 0; j < 4; ++j) acc[i][j] = (f32x4){0.f, 0.f, 0.f, 0.f};

  int offA[4], offB[4];
#pragma unroll
  for (int t = 0; t < 4; ++t) {
    int ra = wm * 64 + t * 16 + l15;
    offA[t] = ra * 32 + ((quad + (ra >> 1)) & 3) * 8;
    int rbn = wn * 64 + t * 16 + l15;
    offB[t] = rbn * 32 + ((quad + (rbn >> 1)) & 3) * 8;
  }

  for (int kb = 0; kb < nkb; ++kb) {
    const unsigned short* g = gbase + (size_t)kb * gstep;
#pragma unroll
    for (int i = 0; i < 8; ++i)
      gl_lds16(g + i * 512, dst + i * 512);
    __syncthreads();

    short8 ah[4], al_[4], bh[4], bl_[4];
#pragma unroll
    for (int t = 0; t < 4; ++t) {
      ah[t]  = *(const short8*)&lAh[offA[t]];
      al_[t] = *(const short8*)&lAl[offA[t]];
      bh[t]  = *(const short8*)&lBh[offB[t]];
      bl_[t] = *(const short8*)&lBl[offB[t]];
    }
#pragma unroll
    for (int tm = 0; tm < 4; ++tm)
#pragma unroll
      for (int tn = 0; tn < 4; ++tn) {
        acc[tm][tn] = __builtin_amdgcn_mfma_f32_16x16x32_bf16(ah[tm], bh[tn], acc[tm][tn], 0, 0, 0);
        acc[tm][tn] = __builtin_amdgcn_mfma_f32_16x16x32_bf16(ah[tm], bl_[tn], acc[tm][tn], 0, 0, 0);
        acc[tm][tn] = __builtin_amdgcn_mfma_f32_16x16x32_bf16(al_[tm], bh[tn], acc[tm][tn], 0, 0, 0);
      }
    __syncthreads();
  }

#pragma unroll
  for (int tm = 0; tm < 4; ++tm) {
    int row = rb * 128 + wm * 64 + tm * 16 + quad * 4;
#pragma unroll
    for (int tn = 0; tn < 4; ++tn) {
      int col = nb * 128 + wn * 64 + tn * 16 + l15;
      bool xlh_half = (col < HC);            // uniform per block (nb<4)
      float bias = xlh_half ? bl[col] : br[col - HC];
#pragma unroll
      for (int r = 0; r < 4; ++r) {
        float v = acc[tm][tn][r] + bias;
        if (xlh_half)
          Chh[(size_t)(row + r) * HC + col] = f2h(v);
        else
          C[(size_t)(row + r) * NC + col] = v;
      }
    }
  }
}

// ================= R15: revert to R11 (best measured: 443 us) =================
// R14 verdict: 4ch/thread forced w[16]=64 VGPR -> occupancy 77->37%, dur 131->192.
// Every structural alternative R4-R14 loses to this configuration: VGPR=32 remat
// + default occupancy (TLP-dominant regime), fp16 xl gathers (byte-cut), full
// 3-kernel fusion, 2-edge ILP. This is the session-best kernel, restored.

__device__ __forceinline__ float edge_logit_g(
    int e, const float* __restrict__ eattr,
    const f32x2* wf0, const f32x2* wf1,
    float2 amv, f32x2 lv, f32x2 rv) {
  f32x4 ea0, ea1, ea2, ea3;
  if (e < EE) {
    const f32x4* ep4 = (const f32x4*)&eattr[(size_t)e * RR];
    ea0 = ep4[0]; ea1 = ep4[1]; ea2 = ep4[2]; ea3 = ep4[3];
  } else {
    ea0 = ea1 = ea2 = ea3 = (f32x4){0.5f, 0.5f, 0.5f, 0.5f};
  }
  f32x2 er[8];
  er[0] = __builtin_shufflevector(ea0, ea0, 0, 1);
  er[1] = __builtin_shufflevector(ea0, ea0, 2, 3);
  er[2] = __builtin_shufflevector(ea1, ea1, 0, 1);
  er[3] = __builtin_shufflevector(ea1, ea1, 2, 3);
  er[4] = __builtin_shufflevector(ea2, ea2, 0, 1);
  er[5] = __builtin_shufflevector(ea2, ea2, 2, 3);
  er[6] = __builtin_shufflevector(ea3, ea3, 0, 1);
  er[7] = __builtin_shufflevector(ea3, ea3, 2, 3);
  f32x2 epp0 = (f32x2){0.f, 0.f};
  f32x2 epp1 = (f32x2){0.f, 0.f};
#pragma unroll
  for (int j = 0; j < 8; ++j) {
    epp0 = __builtin_elementwise_fma(er[j], wf0[j], epp0);   // v_pk_fma_f32
    epp1 = __builtin_elementwise_fma(er[j], wf1[j], epp1);
  }
  float z0 = lv.x + rv.x + (epp0.x + epp0.y);
  float z1 = lv.y + rv.y + (epp1.x + epp1.y);
  z0 = fmaf(0.2f, fminf(z0, 0.f), fmaxf(z0, 0.f));
  z1 = fmaf(0.2f, fminf(z1, 0.f), fmaxf(z1, 0.f));
  float p = fmaf(z0, amv.x, z1 * amv.y);
  p += __shfl_xor(p, 1);
  p += __shfl_xor(p, 2);
  p += __shfl_xor(p, 4);
  p += __shfl_xor(p, 8);
  p += __shfl_xor(p, 16);     // head logit, uniform over 32-lane head group
  return p;
}

__device__ __forceinline__ f32x2 ld_xlh(const unsigned short* __restrict__ xlh,
                                        int s, int c0) {
  unsigned lu = *(const unsigned*)&xlh[(size_t)s * HC + c0];
  return (f32x2){h2f((unsigned short)(lu & 0xFFFFu)),
                 h2f((unsigned short)(lu >> 16))};
}

__device__ __forceinline__ void fused_edge_body(
    const int* __restrict__ csr, const int* __restrict__ srcc,
    const int* __restrict__ offs, const float* __restrict__ eattr,
    const float* __restrict__ WeT, const float* __restrict__ att,
    const float* __restrict__ xlr, const unsigned short* __restrict__ xlh,
    int n, int t, float& out0, float& out1) {
  int c0 = t * 2;
  int beg = offs[n], end = offs[n + 1];
  // per-thread We columns (r-paired for v_pk_fma_f32)
  f32x2 wf0[8], wf1[8];
  {
    const f32x2* w0 = (const f32x2*)&WeT[(size_t)c0 * RR];
    const f32x2* w1 = (const f32x2*)&WeT[(size_t)(c0 + 1) * RR];
#pragma unroll
    for (int j = 0; j < 8; ++j) { wf0[j] = w0[j]; wf1[j] = w1[j]; }
  }
  float2 amv = *(const float2*)&att[c0];
  f32x2 rv = *(const f32x2*)&xlr[(size_t)n * NC + HC + c0];   // dst row: once per block
  float m = -1e30f, l = 0.f;
  f32x2 acc = (f32x2){0.f, 0.f};
  int i = beg;
  for (; i + 2 <= end; i += 2) {
    int e0 = csr[i],     s0 = srcc[i];
    int e1 = csr[i + 1], s1 = srcc[i + 1];
    f32x2 lv0 = ld_xlh(xlh, s0, c0);
    f32x2 lv1 = ld_xlh(xlh, s1, c0);
    float p0 = edge_logit_g(e0, eattr, wf0, wf1, amv, lv0, rv);
    float p1 = edge_logit_g(e1, eattr, wf0, wf1, amv, lv1, rv);
    float nm = fmaxf(fmaxf(m, p0), p1);      // v_max3_f32
    float sc  = __expf(m - nm);
    float el0 = __expf(p0 - nm);
    float el1 = __expf(p1 - nm);
    l = l * sc + el0 + el1;
    acc.x = acc.x * sc + el0 * lv0.x + el1 * lv1.x;
    acc.y = acc.y * sc + el0 * lv0.y + el1 * lv1.y;
    m = nm;
  }
  if (i < end) {
    int e0 = csr[i], s0 = srcc[i];
    f32x2 lv0 = ld_xlh(xlh, s0, c0);
    float p0 = edge_logit_g(e0, eattr, wf0, wf1, amv, lv0, rv);
    float nm = fmaxf(m, p0);
    float sc  = __expf(m - nm);
    float el0 = __expf(p0 - nm);
    l = l * sc + el0;
    acc.x = acc.x * sc + el0 * lv0.x;
    acc.y = acc.y * sc + el0 * lv0.y;
    m = nm;
  }
  float inv = 1.f / (l + 1e-16f);
  out0 = acc.x * inv;
  out1 = acc.y * inv;
}

// layer 1: +bias, emit packed split-bf16 A for layer-2 GEMM
__global__ __launch_bounds__(256) void fused_concat_kernel(
    const int* __restrict__ csr, const int* __restrict__ srcc,
    const int* __restrict__ offs, const float* __restrict__ eattr,
    const float* __restrict__ WeT, const float* __restrict__ att,
    const float* __restrict__ xlr, const unsigned short* __restrict__ xlh,
    const float* __restrict__ bias,
    unsigned short* __restrict__ Ah2, unsigned short* __restrict__ Al2) {
  int n = blockIdx.x, t = threadIdx.x;
  float o0, o1;
  fused_edge_body(csr, srcc, offs, eattr, WeT, att, xlr, xlh, n, t, o0, o1);
  int c0 = t * 2;
  float v0 = o0 + bias[c0];
  float v1 = o1 + bias[c0 + 1];
  int r = n & 127, rbk = n >> 7;
#pragma unroll
  for (int u = 0; u < 2; ++u) {
    int c = c0 + u;
    float v = u ? v1 : v0;
    int kb = c >> 5, ch = (c >> 3) & 3, j = c & 7;
    int chs = (ch + (r >> 1)) & 3;
    size_t idx = ((size_t)rbk * 16 + kb) * 4096 + (size_t)r * 32 + chs * 8 + j;
    unsigned short h = f2bf(v);
    Ah2[idx] = h;
    Al2[idx] = f2bf(v - bf2f(h));
  }
}

// layer 2: mean over heads + bias2 -> out
__global__ __launch_bounds__(256) void fused_mean_kernel(
    const int* __restrict__ csr, const int* __restrict__ srcc,
    const int* __restrict__ offs, const float* __restrict__ eattr,
    const float* __restrict__ WeT, const float* __restrict__ att,
    const float* __restrict__ xlr, const unsigned short* __restrict__ xlh,
    const float* __restrict__ bias2, float* __restrict__ out) {
  __shared__ float red[HC];
  int n = blockIdx.x, t = threadIdx.x;
  float o0, o1;
  fused_edge_body(csr, srcc, offs, eattr, WeT, att, xlr, xlh, n, t, o0, o1);
  int c0 = t * 2;
  red[c0] = o0;
  red[c0 + 1] = o1;
  __syncthreads();
  if (t < CC) {
    float ssum = 0.f;
#pragma unroll
    for (int hh = 0; hh < HH; ++hh) ssum += red[hh * CC + t];
    out[(size_t)n * CC + t] = ssum * 0.125f + bias2[t];
  }
}

extern "C" void kernel_launch(void* const* d_in, const int* in_sizes, int n_in,
                              void* d_out, int out_size, void* d_ws, size_t ws_size,
                              hipStream_t stream) {
  const float* x     = (const float*)d_in[0];
  const int*   ei    = (const int*)d_in[1];
  const float* eattr = (const float*)d_in[2];
  const float* Wl1   = (const float*)d_in[3];
  const float* bl1   = (const float*)d_in[4];
  const float* Wr1   = (const float*)d_in[5];
  const float* br1   = (const float*)d_in[6];
  const float* We1   = (const float*)d_in[7];
  const float* att1  = (const float*)d_in[8];
  const float* bias1 = (const float*)d_in[9];
  const float* Wl2   = (const float*)d_in[10];
  const float* bl2   = (const float*)d_in[11];
  const float* Wr2   = (const float*)d_in[12];
  const float* br2   = (const float*)d_in[13];
  const float* We2   = (const float*)d_in[14];
  const float* att2  = (const float*)d_in[15];
  const float* bias2 = (const float*)d_in[16];
  float* out = (float*)d_out;

  char* ws = (char*)d_ws;
  size_t off = 0;
  auto alloc = [&](size_t bytes) {
    char* p = ws + off;
    off += (bytes + 255) & ~(size_t)255;
    return p;
  };
  float* bufC = (float*)alloc((size_t)NN * NC * 4);            // fused xl|xr (both layers)
  unsigned short* xlh = (unsigned short*)alloc((size_t)NN * HC * 2);  // fp16 xl copy (gather path)
  unsigned short* Ah1 = (unsigned short*)alloc((size_t)NN * FF * 2);
  unsigned short* Al1 = (unsigned short*)alloc((size_t)NN * FF * 2);
  unsigned short* Ah2 = (unsigned short*)alloc((size_t)NN * HC * 2);
  unsigned short* Al2 = (unsigned short*)alloc((size_t)NN * HC * 2);
  unsigned short* Wh1 = (unsigned short*)alloc((size_t)FF * NC * 2);
  unsigned short* Wlo1 = (unsigned short*)alloc((size_t)FF * NC * 2);
  unsigned short* Wh2 = (unsigned short*)alloc((size_t)HC * NC * 2);
  unsigned short* Wlo2 = (unsigned short*)alloc((size_t)HC * NC * 2);
  float* WeT1 = (float*)alloc((size_t)HC * RR * 4);            // We1^T fp32 [512][16]
  float* WeT2 = (float*)alloc((size_t)HC * RR * 4);            // We2^T fp32 [512][16]
  int* counts = (int*)alloc((size_t)NN * 4);
  int* offs   = (int*)alloc((size_t)(NN + 1) * 4);
  int* cursor = (int*)alloc((size_t)NN * 4);
  int* csr    = (int*)alloc((size_t)ET * 4);
  int* srcc   = (int*)alloc((size_t)ET * 4);
  (void)ws_size; (void)in_sizes; (void)n_in; (void)out_size;

  // CSR build (every launch; ws is re-poisoned)
  hipMemsetAsync(counts, 0, (size_t)NN * 4, stream);
  int eb = (ET + 255) / 256;
  count_kernel<<<eb, 256, 0, stream>>>(ei, counts);
  scan_kernel<<<1, 1024, 0, stream>>>(counts, offs, cursor);
  scatter_kernel<<<eb, 256, 0, stream>>>(ei, cursor, csr, srcc);

  // pack operands
  pack_a_kernel<<<(NN / 128) * (FF / 32), 256, 0, stream>>>(x, Ah1, Al1, FF);
  pack_w_kernel<<<(NC / 128) * (FF / 32), 256, 0, stream>>>(Wl1, Wr1, Wh1, Wlo1, FF);
  pack_w_kernel<<<(NC / 128) * (HC / 32), 256, 0, stream>>>(Wl2, Wr2, Wh2, Wlo2, HC);
  pack_wet_kernel<<<(HC * RR) / 256, 256, 0, stream>>>(We1, WeT1);
  pack_wet_kernel<<<(HC * RR) / 256, 256, 0, stream>>>(We2, WeT2);

  dim3 ggrid(NC / 128, NN / 128);

  // ---- layer 1 ----
  gemm_mfma_kernel<<<ggrid, 256, 0, stream>>>(Ah1, Al1, Wh1, Wlo1, bl1, br1, bufC, xlh, FF);
  fused_concat_kernel<<<NN, 256, 0, stream>>>(csr, srcc, offs, eattr, WeT1, att1, bufC, xlh, bias1, Ah2, Al2);

  // ---- layer 2 ----
  gemm_mfma_kernel<<<ggrid, 256, 0, stream>>>(Ah2, Al2, Wh2, Wlo2, bl2, br2, bufC, xlh, HC);
  fused_mean_kernel<<<NN, 256, 0, stream>>>(csr, srcc, offs, eattr, WeT2, att2, bufC, xlh, bias2, out);
}